// Round 11
// baseline (3654.097 us; speedup 1.0000x reference)
//
#include <hip/hip_runtime.h>
#include <math.h>

// Problem constants
#define DD   256
#define TTT  512
#define JJJ  128
#define BBB  32
#define NC   1536     // 6*D combined gate columns (fwd 0..767, bwd 768..1535)
#define ROWS_ALL 36864

typedef _Float16 v2h __attribute__((ext_vector_type(2)));
typedef _Float16 v4h __attribute__((ext_vector_type(4)));
typedef _Float16 v8h __attribute__((ext_vector_type(8)));
typedef short short8 __attribute__((ext_vector_type(8)));
typedef float f32x4 __attribute__((ext_vector_type(4)));

__device__ __forceinline__ short f2bf(float f) {
    unsigned u = __float_as_uint(f);
    unsigned r = (u + 0x7FFFu + ((u >> 16) & 1u)) >> 16;   // RNE
    return (short)r;
}

// ---------------------------------------------------------------------------
// K0: prep — token table, wh16 (fp16 c-major whh concat), biases, Bt bf16, w2h
// ---------------------------------------------------------------------------
__global__ __launch_bounds__(256) void prep_kernel(
    const int* __restrict__ cmnt, const int* __restrict__ src_tok, const int* __restrict__ tgt_tok,
    const float* __restrict__ wih_f, const float* __restrict__ wih_b,
    const float* __restrict__ whh_f, const float* __restrict__ whh_b,
    const float* __restrict__ bih_f, const float* __restrict__ bih_b,
    const float* __restrict__ bhh_f, const float* __restrict__ bhh_b,
    const float* __restrict__ w2,
    int* __restrict__ tok_all, _Float16* __restrict__ wh16,
    float* __restrict__ bihc, float* __restrict__ bhhc, short* __restrict__ Bt,
    _Float16* __restrict__ w2h)
{
    const int idx = blockIdx.x * blockDim.x + threadIdx.x;
    const int stride = gridDim.x * blockDim.x;
    for (int i = idx; i < ROWS_ALL; i += stride)
        tok_all[i] = (i < 16384) ? src_tok[i] : (i < 32768) ? tgt_tok[i - 16384] : cmnt[i - 32768];
    for (int i = idx; i < 393216; i += stride)
        wh16[i] = (_Float16)(i < 196608 ? whh_f[i] : whh_b[i - 196608]);
    for (int i = idx; i < 393216; i += stride)
        Bt[i] = f2bf(i < 196608 ? wih_f[i] : wih_b[i - 196608]);
    for (int i = idx; i < NC; i += stride) {
        bihc[i] = (i < 768) ? bih_f[i] : bih_b[i - 768];
        bhhc[i] = (i < 768) ? bhh_f[i] : bhh_b[i - 768];
    }
    for (int i = idx; i < 512; i += stride)
        w2h[i] = (_Float16)w2[i];
}

// K0b: gather token embedding rows to bf16 A matrix (nrows x 256)
__global__ __launch_bounds__(256) void gatherA_kernel(
    const int* __restrict__ tok, int nrows,
    const float* __restrict__ emb, short* __restrict__ A)
{
    const int idx = blockIdx.x * blockDim.x + threadIdx.x;
    const int stride = gridDim.x * blockDim.x;
    const int ngroups = nrows * 64;
    for (int g = idx; g < ngroups; g += stride) {
        const int i = g >> 6;
        const int kq = (g & 63) << 2;
        const float4 v = *(const float4*)(emb + (size_t)tok[i] * 256 + kq);
        short4 s;
        s.x = f2bf(v.x); s.y = f2bf(v.y); s.z = f2bf(v.z); s.w = f2bf(v.w);
        *(short4*)(A + (size_t)i * 256 + kq) = s;
    }
}

// ---------------------------------------------------------------------------
// K1: FUSED gi GEMM + swizzle. One block per t-slot T (1152 blocks, 512 thr).
// Computes gi[b=0..31][c=0..1535] for this (seq,t) via bf16 MFMA (M=32,
// N=1536, K=256; wave w owns cols w*192..+191), then re-stages through LDS
// so the output lands in the gru-swizzled layout with COALESCED 16B stores:
//   gswz[((T*4 + dir*2 + bhalf)*512 + tid')*24 + g*8 + u*4 + reg]
// (tid' = w'*64 + quad*16 + l16; col = dir*768 + g*256 + w'*32 + u*16 + l16;
//  b = bhalf*16 + quad*4 + reg). bhh_r/z folded into bias (g<2).
// ---------------------------------------------------------------------------
__global__ __launch_bounds__(512) void gis_mfma(
    const short* __restrict__ A, const short* __restrict__ Bt,
    const float* __restrict__ bihc, const float* __restrict__ bhhc,
    _Float16* __restrict__ gswz)
{
    const int T = blockIdx.x;
    const int seq = (T < 512) ? 0 : (T < 1024) ? 1 : 2;
    const int t = T - ((seq == 0) ? 0 : (seq == 1) ? 512 : 1024);
    const int Tlen = (seq == 2) ? 128 : 512;
    const int seqArow = (seq == 0) ? 0 : (seq == 1) ? 16384 : 32768;

    __shared__ __align__(16) char ldsraw[51200];
    short* Asl = (short*)ldsraw;          // phase 1/2: A stage [32][264]
    _Float16* stg = (_Float16*)ldsraw;    // phase 3:  out stage [1024][25]

    const int tid = threadIdx.x;
    const int w = tid >> 6, lane = tid & 63;
    const int quad = lane >> 4, l16 = lane & 15;

    // Phase 1: stage A rows (32 x 256 bf16) into LDS, coalesced.
    for (int i = tid; i < 1024; i += 512) {
        const int b = i >> 5, ch = i & 31;
        *(short8*)&Asl[b * 264 + ch * 8] =
            *(const short8*)(A + (size_t)(seqArow + b * Tlen + t) * 256 + ch * 8);
    }
    __syncthreads();

    // Phase 2: MFMA. acc[mt][nt], mt = b-half, nt over this wave's 12 n-tiles.
    f32x4 acc[2][12];
    #pragma unroll
    for (int mt = 0; mt < 2; ++mt)
        #pragma unroll
        for (int nt = 0; nt < 12; ++nt) acc[mt][nt] = (f32x4){0.f, 0.f, 0.f, 0.f};
    float bias[12];
    #pragma unroll
    for (int nt = 0; nt < 12; ++nt) {
        const int c = w * 192 + nt * 16 + l16;
        const int g = (c - ((c >= 768) ? 768 : 0)) >> 8;
        bias[nt] = bihc[c] + ((g < 2) ? bhhc[c] : 0.f);
    }
    for (int ks = 0; ks < 8; ++ks) {
        const short8 a0 = *(const short8*)&Asl[l16 * 264 + ks * 32 + quad * 8];
        const short8 a1 = *(const short8*)&Asl[(16 + l16) * 264 + ks * 32 + quad * 8];
        #pragma unroll
        for (int nt = 0; nt < 12; ++nt) {
            const short8 bf = *(const short8*)(Bt + (size_t)(w * 192 + nt * 16 + l16) * 256 + ks * 32 + quad * 8);
            acc[0][nt] = __builtin_amdgcn_mfma_f32_16x16x32_bf16(a0, bf, acc[0][nt], 0, 0, 0);
            acc[1][nt] = __builtin_amdgcn_mfma_f32_16x16x32_bf16(a1, bf, acc[1][nt], 0, 0, 0);
        }
    }

    // Phase 3: per-dir LDS re-stage -> coalesced swizzled global writes.
    const int mydir = w >> 2;                 // waves 0-3 own dir 0 cols, 4-7 dir 1
    for (int dir = 0; dir < 2; ++dir) {
        __syncthreads();                      // Asl reads / prior stg reads done
        if (mydir == dir) {
            #pragma unroll
            for (int nt = 0; nt < 12; ++nt) {
                const int c = w * 192 + nt * 16 + l16;
                const int jloc = (c - dir * 768) & 255;
                const int g = (c - dir * 768) >> 8;
                const int u = (jloc >> 4) & 1;
                const int obase = (jloc >> 5) * 64 + quad * 16 + (jloc & 15);
                #pragma unroll
                for (int mt = 0; mt < 2; ++mt)
                    #pragma unroll
                    for (int reg = 0; reg < 4; ++reg)
                        stg[(size_t)(mt * 512 + obase) * 25 + g * 8 + u * 4 + reg] =
                            (_Float16)(acc[mt][nt][reg] + bias[nt]);
            }
        }
        __syncthreads();
        _Float16* outb = gswz + ((size_t)(T * 4 + dir * 2)) * 512 * 24;
        for (int ot = tid; ot < 1024; ot += 512) {
            v8h o0, o1, o2;
            #pragma unroll
            for (int p = 0; p < 8; ++p) {
                o0[p] = stg[(size_t)ot * 25 + p];
                o1[p] = stg[(size_t)ot * 25 + 8 + p];
                o2[p] = stg[(size_t)ot * 25 + 16 + p];
            }
            _Float16* dst = outb + (size_t)ot * 24;
            *(v8h*)dst = o0;
            *(v8h*)(dst + 8) = o1;
            *(v8h*)(dst + 16) = o2;
        }
    }
}

// ---------------------------------------------------------------------------
// K2: GRU recurrence via f16 MFMA across batch (R10 structure, fixed gi path).
// 12 blocks = (chain) x (bhalf); 512 thr = 8 waves (2/SIMD, 256 unified cap).
//   r,z weights: 128 regs/lane resident. n weights: LDS (133 KB).
//   hbuf pitch 260 (2-way banks = free). lgkm-only barrier per step.
//   gi: THREE dwordx4 loads from one pointer w/ immediate offsets (swizzled
//   by gis_mfma) — replaces R10's 24 serialized scalar loads.
// ---------------------------------------------------------------------------
#define HP 260
__global__ __launch_bounds__(512, 2) void gru_kernel(
    const _Float16* __restrict__ gswz, const _Float16* __restrict__ wh16,
    const float* __restrict__ bhhc,
    _Float16* __restrict__ e_src, _Float16* __restrict__ e_tgt, _Float16* __restrict__ e_cmnt)
{
    const int chain = (int)(blockIdx.x >> 1);
    const int bhalf = (int)(blockIdx.x & 1);
    const int seq = chain >> 1, dir = chain & 1;
    const int Tlen = (seq == 2) ? JJJ : TTT;
    const int seqTbase = (seq == 0) ? 0 : (seq == 1) ? 512 : 1024;
    _Float16* e = (seq == 0) ? e_src : (seq == 1) ? e_tgt : e_cmnt;
    const int cb = dir * 768;

    const int tid = threadIdx.x;
    const int w = tid >> 6, lane = tid & 63;
    const int quad = lane >> 4, l16 = lane & 15;
    const int j0 = w * 32;

    __shared__ __align__(16) _Float16 wnlds[256 * HP];     // n-gate weights
    __shared__ __align__(16) _Float16 hbuf[2][16 * HP];

    for (int idx = tid; idx < 256 * 32; idx += 512) {
        const int row = idx >> 5, ch = idx & 31;
        *(v8h*)&wnlds[row * HP + ch * 8] =
            *(const v8h*)(wh16 + (size_t)(cb + 512 + row) * 256 + ch * 8);
    }
    v8h Wrz[2][2][8];
    #pragma unroll
    for (int g = 0; g < 2; ++g)
        #pragma unroll
        for (int u = 0; u < 2; ++u) {
            const _Float16* wrow = wh16 + (size_t)(cb + g * 256 + j0 + u * 16 + l16) * 256 + quad * 8;
            #pragma unroll
            for (int ks = 0; ks < 8; ++ks)
                Wrz[g][u][ks] = *(const v8h*)(wrow + ks * 32);
        }

    float bhn[2];
    #pragma unroll
    for (int u = 0; u < 2; ++u) bhn[u] = bhhc[cb + 512 + j0 + u * 16 + l16];

    float hp[2][4];
    #pragma unroll
    for (int u = 0; u < 2; ++u)
        #pragma unroll
        for (int reg = 0; reg < 4; ++reg) hp[u][reg] = 0.f;

    for (int i = tid; i < 16 * HP; i += 512) hbuf[0][i] = (_Float16)0.f;
    __syncthreads();

    const int t0 = dir ? (Tlen - 1) : 0;
    const long tstep = dir ? -1L : 1L;
    const _Float16* gp = gswz
        + ((size_t)((seqTbase + t0) * 4 + dir * 2 + bhalf) * 512 + (size_t)tid) * 24;
    const long gistep = tstep * 49152;        // 4*512*24 halfs per t

    _Float16* ecur = e + ((size_t)(bhalf * 16 + quad * 4) * Tlen + t0) * 512 + dir * 256 + j0 + l16;
    const long estep = tstep * 512;
    const long eregstride = (long)Tlen * 512;

    for (int s = 0; s < Tlen; ++s) {
        // gi: 3 vector loads, one base, immediate offsets — cannot serialize
        const v8h g0 = *(const v8h*)(gp);
        const v8h g1 = *(const v8h*)(gp + 8);
        const v8h g2 = *(const v8h*)(gp + 16);

        f32x4 acc[3][2];
        #pragma unroll
        for (int g = 0; g < 3; ++g)
            #pragma unroll
            for (int u = 0; u < 2; ++u) acc[g][u] = (f32x4){0.f, 0.f, 0.f, 0.f};

        const _Float16* hb = &hbuf[s & 1][l16 * HP + quad * 8];
        const _Float16* wn0 = &wnlds[(j0 + l16) * HP + quad * 8];
        const _Float16* wn1 = &wnlds[(j0 + 16 + l16) * HP + quad * 8];
        #pragma unroll
        for (int ks = 0; ks < 8; ++ks) {
            const v8h Af = *(const v8h*)(hb + ks * 32);
            const v8h Bn0 = *(const v8h*)(wn0 + ks * 32);
            const v8h Bn1 = *(const v8h*)(wn1 + ks * 32);
            acc[0][0] = __builtin_amdgcn_mfma_f32_16x16x32_f16(Af, Wrz[0][0][ks], acc[0][0], 0, 0, 0);
            acc[0][1] = __builtin_amdgcn_mfma_f32_16x16x32_f16(Af, Wrz[0][1][ks], acc[0][1], 0, 0, 0);
            acc[1][0] = __builtin_amdgcn_mfma_f32_16x16x32_f16(Af, Wrz[1][0][ks], acc[1][0], 0, 0, 0);
            acc[1][1] = __builtin_amdgcn_mfma_f32_16x16x32_f16(Af, Wrz[1][1][ks], acc[1][1], 0, 0, 0);
            acc[2][0] = __builtin_amdgcn_mfma_f32_16x16x32_f16(Af, Bn0, acc[2][0], 0, 0, 0);
            acc[2][1] = __builtin_amdgcn_mfma_f32_16x16x32_f16(Af, Bn1, acc[2][1], 0, 0, 0);
        }

        // gates in-register; C-layout: col=l16 (j), row=quad*4+reg (b)
        _Float16* hw = &hbuf[(s + 1) & 1][(quad * 4) * HP + j0 + l16];
        #pragma unroll
        for (int u = 0; u < 2; ++u) {
            #pragma unroll
            for (int reg = 0; reg < 4; ++reg) {
                const float gr = acc[0][u][reg] + (float)g0[u * 4 + reg];
                const float gz = acc[1][u][reg] + (float)g1[u * 4 + reg];
                const float r = 1.f / (1.f + __expf(-gr));
                const float z = 1.f / (1.f + __expf(-gz));
                const float x = (float)g2[u * 4 + reg] + r * (acc[2][u][reg] + bhn[u]);
                const float ex = __expf(2.f * x);
                const float n = 1.f - 2.f / (ex + 1.f);        // tanh(x)
                const float hnew = (1.f - z) * n + z * hp[u][reg];
                hp[u][reg] = hnew;
                ecur[(long)reg * eregstride + u * 16] = (_Float16)hnew;   // async
                hw[reg * HP + u * 16] = (_Float16)hnew;
            }
        }
        gp += gistep;
        ecur += estep;
        asm volatile("s_waitcnt lgkmcnt(0)\n\ts_barrier" ::: "memory");
    }
}

// ---------------------------------------------------------------------------
// K3: sim via f16 MFMA 16x16x32.  S[b,t,j] = sum_d (ctx*w2)[t,d]*ec[j,d] + act
// ---------------------------------------------------------------------------
#define LP 40
__global__ __launch_bounds__(256) void sim_mfma(
    const _Float16* __restrict__ e_src, const _Float16* __restrict__ e_tgt,
    const _Float16* __restrict__ e_cmnt, const _Float16* __restrict__ w2h,
    const float* __restrict__ w2,
    const int* __restrict__ src_action, const int* __restrict__ tgt_action,
    float* __restrict__ S, float* __restrict__ rowmaxP)
{
    const int sb = (int)blockIdx.z;
    const int seq = sb >> 5, b = sb & 31;
    const int t0 = blockIdx.x * 128;
    const _Float16* ctx = ((seq == 0) ? e_src : e_tgt) + (size_t)b * 512 * 512;
    const _Float16* ec = e_cmnt + (size_t)b * 128 * 512;
    const int* act = (seq == 0) ? src_action : tgt_action;

    __shared__ __align__(16) _Float16 As[128 * LP];
    __shared__ __align__(16) _Float16 Bs[128 * LP];
    const int tid = threadIdx.x;
    const int wave = tid >> 6, lane = tid & 63;
    const int quad = lane >> 4, l16 = lane & 15;
    const int wm = (wave & 1) * 64, wn = (wave >> 1) * 64;
    const int sr = tid >> 2;
    const int sk = (tid & 3) * 8;

    const _Float16* ga0 = ctx + (size_t)(t0 + sr) * 512 + sk;
    const _Float16* ga1 = ctx + (size_t)(t0 + sr + 64) * 512 + sk;
    const _Float16* gb0 = ec + (size_t)sr * 512 + sk;
    const _Float16* gb1 = ec + (size_t)(sr + 64) * 512 + sk;

    f32x4 acc[4][4];
    #pragma unroll
    for (int i = 0; i < 4; ++i)
        #pragma unroll
        for (int j = 0; j < 4; ++j) acc[i][j] = (f32x4){0.f, 0.f, 0.f, 0.f};

    for (int k0 = 0; k0 < 512; k0 += 32) {
        v8h a0 = *(const v8h*)(ga0 + k0);
        v8h a1 = *(const v8h*)(ga1 + k0);
        const v8h b0 = *(const v8h*)(gb0 + k0);
        const v8h b1 = *(const v8h*)(gb1 + k0);
        const v8h w8 = *(const v8h*)(w2h + k0 + sk);
        a0 = a0 * w8;
        a1 = a1 * w8;
        __syncthreads();
        *(v8h*)&As[sr * LP + sk] = a0;
        *(v8h*)&As[(sr + 64) * LP + sk] = a1;
        *(v8h*)&Bs[sr * LP + sk] = b0;
        *(v8h*)&Bs[(sr + 64) * LP + sk] = b1;
        __syncthreads();
        v8h af[4], bf[4];
        #pragma unroll
        for (int i = 0; i < 4; ++i)
            af[i] = *(const v8h*)&As[(wm + i * 16 + l16) * LP + quad * 8];
        #pragma unroll
        for (int j = 0; j < 4; ++j)
            bf[j] = *(const v8h*)&Bs[(wn + j * 16 + l16) * LP + quad * 8];
        #pragma unroll
        for (int i = 0; i < 4; ++i)
            #pragma unroll
            for (int j = 0; j < 4; ++j)
                acc[i][j] = __builtin_amdgcn_mfma_f32_16x16x32_f16(af[i], bf[j], acc[i][j], 0, 0, 0);
    }

    const float w2a = w2[512];
    #pragma unroll
    for (int i = 0; i < 4; ++i) {
        #pragma unroll
        for (int reg = 0; reg < 4; ++reg) {
            const int t = t0 + wm + i * 16 + quad * 4 + reg;
            const float aterm = (float)act[b * 512 + t] * w2a;
            float m = -1e30f;
            #pragma unroll
            for (int j = 0; j < 4; ++j) {
                const float v = acc[i][j][reg] + aterm;
                S[((size_t)(sb * 512 + t)) * 128 + wn + j * 16 + l16] = v;
                m = fmaxf(m, v);
            }
            m = fmaxf(m, __shfl_xor(m, 1));
            m = fmaxf(m, __shfl_xor(m, 2));
            m = fmaxf(m, __shfl_xor(m, 4));
            m = fmaxf(m, __shfl_xor(m, 8));
            if (l16 == 0)
                rowmaxP[(size_t)(wave >> 1) * 32768 + sb * 512 + t] = m;
        }
    }
}

// K5: softmax over t (512) per (seq,b)
__global__ __launch_bounds__(256) void softmax_kernel(const float* __restrict__ rowmaxP, float* __restrict__ bw)
{
    const int base = blockIdx.x * 512;
    const int tid = threadIdx.x;
    __shared__ float red[256];
    const float v0 = fmaxf(rowmaxP[base + tid], rowmaxP[32768 + base + tid]);
    const float v1 = fmaxf(rowmaxP[base + 256 + tid], rowmaxP[32768 + base + 256 + tid]);
    red[tid] = fmaxf(v0, v1);
    __syncthreads();
    for (int off = 128; off > 0; off >>= 1) {
        if (tid < off) red[tid] = fmaxf(red[tid], red[tid + off]);
        __syncthreads();
    }
    const float M = red[0];
    __syncthreads();
    const float e0 = __expf(v0 - M), e1 = __expf(v1 - M);
    red[tid] = e0 + e1;
    __syncthreads();
    for (int off = 128; off > 0; off >>= 1) {
        if (tid < off) red[tid] += red[tid + off];
        __syncthreads();
    }
    const float inv = 1.f / red[0];
    bw[base + tid] = e0 * inv;
    bw[base + 256 + tid] = e1 * inv;
}

// K6: outSP[c][sb*128+j] = sum_{t in chunk c} bw[sb,t] * S[sb,t,j]
__global__ __launch_bounds__(256) void weighted_kernel(
    const float* __restrict__ S, const float* __restrict__ bw, float* __restrict__ outSP)
{
    const int sb = blockIdx.x;
    const int ch = blockIdx.y;
    const int tid = threadIdx.x;
    const int j = tid & 127, half = tid >> 7;
    const float* Sb = S + (size_t)sb * 512 * 128;
    const float* w = bw + sb * 512;
    const int tb = ch * 64 + half * 32;
    float acc = 0.f;
    for (int t = tb; t < tb + 32; ++t)
        acc = fmaf(w[t], Sb[(size_t)t * 128 + j], acc);
    __shared__ float red[256];
    red[tid] = acc;
    __syncthreads();
    if (half == 0) outSP[(size_t)ch * 8192 + sb * 128 + j] = red[j] + red[128 + j];
}

// K7: sum chunk partials; write S_diff and result into d_out
__global__ __launch_bounds__(256) void final_kernel(
    const float* __restrict__ outSP, const float* __restrict__ rank_w,
    const float* __restrict__ rank_b, float* __restrict__ out)
{
    __shared__ float sArr[8192];
    const int tid = threadIdx.x;
    for (int q = tid; q < 8192; q += 256) {
        float s = 0.f;
        #pragma unroll
        for (int c = 0; c < 8; ++c) s += outSP[(size_t)c * 8192 + q];
        sArr[q] = s;
    }
    __syncthreads();
    for (int q = tid; q < 8192; q += 256) {
        const int b = q >> 8, c = q & 255;
        out[32 + q] = (c < 128) ? sArr[b * 128 + c] : sArr[4096 + b * 128 + (c - 128)];
    }
    if (tid < 32) {
        float acc = rank_b[0];
        for (int c = 0; c < 128; ++c) acc = fmaf(sArr[tid * 128 + c], rank_w[c], acc);
        for (int c = 0; c < 128; ++c) acc = fmaf(sArr[4096 + tid * 128 + c], rank_w[128 + c], acc);
        out[tid] = acc;
    }
}

// ---------------------------------------------------------------------------
extern "C" void kernel_launch(void* const* d_in, const int* in_sizes, int n_in,
                              void* d_out, int out_size, void* d_ws, size_t ws_size,
                              hipStream_t stream)
{
    const int* cmnt       = (const int*)d_in[0];
    const int* src_token  = (const int*)d_in[1];
    const int* tgt_token  = (const int*)d_in[2];
    const int* src_action = (const int*)d_in[3];
    const int* tgt_action = (const int*)d_in[4];
    const float* emb    = (const float*)d_in[5];
    const float* wih_f  = (const float*)d_in[6];
    const float* whh_f  = (const float*)d_in[7];
    const float* bih_f  = (const float*)d_in[8];
    const float* bhh_f  = (const float*)d_in[9];
    const float* wih_b  = (const float*)d_in[10];
    const float* whh_b  = (const float*)d_in[11];
    const float* bih_b  = (const float*)d_in[12];
    const float* bhh_b  = (const float*)d_in[13];
    const float* w2     = (const float*)d_in[14];
    const float* rank_w = (const float*)d_in[15];
    const float* rank_b = (const float*)d_in[16];
    float* out = (float*)d_out;

    // Workspace (fp32 slots). Same 171 MB footprint as the proven R6 tier-A.
    float* ws = (float*)d_ws;
    size_t off = 0;
    int*   tok_all = (int*)(ws + off); off += 36864;
    short* Bt_bf16 = (short*)(ws + off); off += 196608;        // 1536x256 bf16
    _Float16* wh16 = (_Float16*)(ws + off); off += 196608;     // 1536x256 fp16
    float* bihc   = ws + off; off += 1536;
    float* bhhc   = ws + off; off += 1536;
    _Float16* w2h = (_Float16*)(ws + off); off += 256;
    float* rowmaxP = ws + off; off += 65536;
    float* bw     = ws + off; off += 32768;
    float* outSP  = ws + off; off += 65536;
    _Float16* e_src  = (_Float16*)(ws + off); off += 4194304;
    _Float16* e_tgt  = (_Float16*)(ws + off); off += 4194304;
    _Float16* e_cmnt = (_Float16*)(ws + off); off += 1048576;
    float* S      = ws + off; off += 4194304;
    _Float16* gswz = (_Float16*)(ws + off);                    // 1152*4*512*24 halfs

    hipLaunchKernelGGL(prep_kernel, dim3(512), dim3(256), 0, stream,
        cmnt, src_token, tgt_token, wih_f, wih_b, whh_f, whh_b,
        bih_f, bih_b, bhh_f, bhh_b, w2, tok_all, wh16, bihc, bhhc, Bt_bf16, w2h);

    // A_bf16 aliases e_src+e_tgt, consumed before gru writes e.
    short* A = (short*)e_src;
    hipLaunchKernelGGL(gatherA_kernel, dim3(4096), dim3(256), 0, stream,
        tok_all, 36864, emb, A);
    hipLaunchKernelGGL(gis_mfma, dim3(1152), dim3(512), 0, stream,
        A, Bt_bf16, bihc, bhhc, gswz);
    hipLaunchKernelGGL(gru_kernel, dim3(12), dim3(512), 0, stream,
        gswz, wh16, bhhc, e_src, e_tgt, e_cmnt);

    hipLaunchKernelGGL(sim_mfma, dim3(4, 1, 64), dim3(256), 0, stream,
        e_src, e_tgt, e_cmnt, w2h, w2, src_action, tgt_action, S, rowmaxP);
    hipLaunchKernelGGL(softmax_kernel, dim3(64), dim3(256), 0, stream, rowmaxP, bw);
    hipLaunchKernelGGL(weighted_kernel, dim3(64, 8), dim3(256), 0, stream, S, bw, outSP);
    hipLaunchKernelGGL(final_kernel, dim3(1), dim3(256), 0, stream, outSP, rank_w, rank_b, out);
}

// Round 12
// 843.238 us; speedup vs baseline: 4.3334x; 4.3334x over previous
//
#include <hip/hip_runtime.h>
#include <math.h>

// Problem constants
#define DD   256      // word_embd_size
#define TTT  512      // T
#define JJJ  128      // J
#define BBB  32       // B
#define NC   1536     // 6*D combined gate columns (fwd 0..767, bwd 768..1535)
#define ROWS_ALL 36864

typedef _Float16 v2h __attribute__((ext_vector_type(2)));
typedef _Float16 v4h __attribute__((ext_vector_type(4)));
typedef _Float16 v8h __attribute__((ext_vector_type(8)));
typedef short short8 __attribute__((ext_vector_type(8)));
typedef float f32x4 __attribute__((ext_vector_type(4)));

#if __has_builtin(__builtin_amdgcn_fdot2)
#define FDOT2(a, b, c) __builtin_amdgcn_fdot2((a), (b), (c), false)
#else
#define FDOT2(a, b, c) ((float)(a)[0] * (float)(b)[0] + ((float)(a)[1] * (float)(b)[1] + (c)))
#endif

__device__ __forceinline__ short f2bf(float f) {
    unsigned u = __float_as_uint(f);
    unsigned r = (u + 0x7FFFu + ((u >> 16) & 1u)) >> 16;   // RNE
    return (short)r;
}

// ---------------------------------------------------------------------------
// K0: prep — token table, whhT (k-major for gru), biases, Bt bf16, w2 fp16
// ---------------------------------------------------------------------------
__global__ __launch_bounds__(256) void prep_kernel(
    const int* __restrict__ cmnt, const int* __restrict__ src_tok, const int* __restrict__ tgt_tok,
    const float* __restrict__ wih_f, const float* __restrict__ wih_b,
    const float* __restrict__ whh_f, const float* __restrict__ whh_b,
    const float* __restrict__ bih_f, const float* __restrict__ bih_b,
    const float* __restrict__ bhh_f, const float* __restrict__ bhh_b,
    const float* __restrict__ w2,
    int* __restrict__ tok_all, float* __restrict__ whhT,
    float* __restrict__ bihc, float* __restrict__ bhhc, short* __restrict__ Bt,
    _Float16* __restrict__ w2h)
{
    const int idx = blockIdx.x * blockDim.x + threadIdx.x;
    const int stride = gridDim.x * blockDim.x;
    for (int i = idx; i < ROWS_ALL; i += stride)
        tok_all[i] = (i < 16384) ? src_tok[i] : (i < 32768) ? tgt_tok[i - 16384] : cmnt[i - 32768];
    for (int i = idx; i < 256 * NC; i += stride) {
        const int k = i / NC, c = i % NC;
        whhT[i] = (c < 768) ? whh_f[(size_t)c * 256 + k] : whh_b[(size_t)(c - 768) * 256 + k];
    }
    for (int i = idx; i < 393216; i += stride)
        Bt[i] = f2bf(i < 196608 ? wih_f[i] : wih_b[i - 196608]);
    for (int i = idx; i < NC; i += stride) {
        bihc[i] = (i < 768) ? bih_f[i] : bih_b[i - 768];
        bhhc[i] = (i < 768) ? bhh_f[i] : bhh_b[i - 768];
    }
    for (int i = idx; i < 512; i += stride)
        w2h[i] = (_Float16)w2[i];
}

// K0b: gather token embedding rows to bf16 A matrix (nrows x 256)
__global__ __launch_bounds__(256) void gatherA_kernel(
    const int* __restrict__ tok, int row_start, int nrows,
    const float* __restrict__ emb, short* __restrict__ A)
{
    const int idx = blockIdx.x * blockDim.x + threadIdx.x;
    const int stride = gridDim.x * blockDim.x;
    const int ngroups = nrows * 64;                  // 4 elems per group
    for (int g = idx; g < ngroups; g += stride) {
        const int i = g >> 6;
        const int kq = (g & 63) << 2;
        const float4 v = *(const float4*)(emb + (size_t)tok[row_start + i] * 256 + kq);
        short4 s;
        s.x = f2bf(v.x); s.y = f2bf(v.y); s.z = f2bf(v.z); s.w = f2bf(v.w);
        *(short4*)(A + (size_t)i * 256 + kq) = s;
    }
}

// ---------------------------------------------------------------------------
// K1: gi GEMM via bf16 MFMA 16x16x32 with LDS-staged tiles; fp16 output.
// BM=BN=128, BK=32; 256 thr (2x2 waves of 64x64), padded LDS rows.
// ---------------------------------------------------------------------------
#define LP 40   // padded LDS row pitch in 2-byte units
__global__ __launch_bounds__(256) void gi_mfma(
    const short* __restrict__ A, const short* __restrict__ Bt,
    const float* __restrict__ bihc, _Float16* __restrict__ gi)
{
    __shared__ __align__(16) short As[128 * LP];
    __shared__ __align__(16) short Bs[128 * LP];
    const int tid = threadIdx.x;
    const int wave = tid >> 6, lane = tid & 63;
    const int quad = lane >> 4, l16 = lane & 15;
    const int m0 = blockIdx.x * 128, n0 = blockIdx.y * 128;
    const int wm = (wave & 1) * 64, wn = (wave >> 1) * 64;

    const int sr = tid >> 2;            // 0..63 (staging row)
    const int sk = (tid & 3) * 8;       // 0,8,16,24 (staging k)
    const short* ga0 = A  + (size_t)(m0 + sr) * 256 + sk;
    const short* ga1 = A  + (size_t)(m0 + sr + 64) * 256 + sk;
    const short* gb0 = Bt + (size_t)(n0 + sr) * 256 + sk;
    const short* gb1 = Bt + (size_t)(n0 + sr + 64) * 256 + sk;

    f32x4 acc[4][4];
    #pragma unroll
    for (int i = 0; i < 4; ++i)
        #pragma unroll
        for (int j = 0; j < 4; ++j) acc[i][j] = (f32x4){0.f, 0.f, 0.f, 0.f};

    for (int k0 = 0; k0 < 256; k0 += 32) {
        const short8 a0 = *(const short8*)(ga0 + k0);
        const short8 a1 = *(const short8*)(ga1 + k0);
        const short8 b0 = *(const short8*)(gb0 + k0);
        const short8 b1 = *(const short8*)(gb1 + k0);
        __syncthreads();                               // prior frag reads done
        *(short8*)&As[sr * LP + sk] = a0;
        *(short8*)&As[(sr + 64) * LP + sk] = a1;
        *(short8*)&Bs[sr * LP + sk] = b0;
        *(short8*)&Bs[(sr + 64) * LP + sk] = b1;
        __syncthreads();                               // tiles visible
        short8 af[4], bf[4];
        #pragma unroll
        for (int i = 0; i < 4; ++i)
            af[i] = *(const short8*)&As[(wm + i * 16 + l16) * LP + quad * 8];
        #pragma unroll
        for (int j = 0; j < 4; ++j)
            bf[j] = *(const short8*)&Bs[(wn + j * 16 + l16) * LP + quad * 8];
        #pragma unroll
        for (int i = 0; i < 4; ++i)
            #pragma unroll
            for (int j = 0; j < 4; ++j)
                acc[i][j] = __builtin_amdgcn_mfma_f32_16x16x32_bf16(af[i], bf[j], acc[i][j], 0, 0, 0);
    }

    #pragma unroll
    for (int j = 0; j < 4; ++j) {
        const int col = n0 + wn + j * 16 + l16;
        const float bias = bihc[col];
        #pragma unroll
        for (int i = 0; i < 4; ++i) {
            const int r0 = m0 + wm + i * 16 + quad * 4;
            #pragma unroll
            for (int reg = 0; reg < 4; ++reg)
                gi[(size_t)(r0 + reg) * NC + col] = (_Float16)(acc[i][j][reg] + bias);
        }
    }
}

// ---------------------------------------------------------------------------
// K2: GRU recurrence — fp16-packed register-resident weights.
// 192 blocks x 512 threads (8 waves); j = tid&255, q = tid>>8 (k-half).
// e-store delayed one step; tanh via inline __expf. [R7-proven: 675 us]
// ---------------------------------------------------------------------------
__global__ __launch_bounds__(512, 2) void gru_kernel(
    const _Float16* __restrict__ gi0, const _Float16* __restrict__ gi1, const _Float16* __restrict__ gi2,
    const float* __restrict__ whhT, const float* __restrict__ bhhc,
    _Float16* __restrict__ e_src, _Float16* __restrict__ e_tgt, _Float16* __restrict__ e_cmnt,
    int chain_base)
{
    const int chain = chain_base + (int)(blockIdx.x >> 5);
    const int b = (int)(blockIdx.x & 31);
    const int seq = chain >> 1, dir = chain & 1;
    const int Tlen = (seq == 2) ? JJJ : TTT;
    const _Float16* gi = (seq == 0) ? gi0 : (seq == 1) ? gi1 : gi2;
    _Float16* e = (seq == 0) ? e_src : (seq == 1) ? e_tgt : e_cmnt;

    const int tid = threadIdx.x;
    const int j = tid & 255;
    const int q = tid >> 8;
    const int cb = dir * 768;

    __shared__ __align__(16) v2h h2s[128];
    __shared__ float parts[3][256];

    // One-time weight load: fp32 from L2, packed to half2 registers.
    v2h wr2[64], wz2[64], wn2[64];
    {
        const float* wb = whhT + (size_t)(q * 128) * NC + cb + j;
        #pragma unroll
        for (int p = 0; p < 64; ++p) {
            v2h a, bzv, c;
            a[0]   = (_Float16)wb[0];        a[1]   = (_Float16)wb[NC];
            bzv[0] = (_Float16)wb[256];      bzv[1] = (_Float16)wb[NC + 256];
            c[0]   = (_Float16)wb[512];      c[1]   = (_Float16)wb[NC + 512];
            wr2[p] = a; wz2[p] = bzv; wn2[p] = c;
            wb += 2 * NC;
        }
    }
    const float br  = bhhc[cb + j];
    const float bzb = bhhc[cb + 256 + j];
    const float bnb = bhhc[cb + 512 + j];

    float hprev = 0.f;                      // q==0 thread j owns h[j]
    if (q == 0 && (j & 1) == 0) {
        v2h z0; z0[0] = (_Float16)0.f; z0[1] = (_Float16)0.f;
        h2s[j >> 1] = z0;
    }
    __syncthreads();

    const int t0i = dir ? (Tlen - 1) : 0;
    const long tstep = dir ? -1 : 1;
    const _Float16* girow = gi + (size_t)(b * Tlen + t0i) * NC + cb;
    _Float16* eptr = e + (size_t)(b * Tlen + t0i) * 512 + (dir << 8) + j;
    const long gstep = tstep * NC;
    const long estep = tstep * 512;

    _Float16* pptr = eptr;                  // pending e-store (delayed 1 step)
    float pval = 0.f;

    for (int s = 0; s < Tlen; ++s) {
        // delayed e-store + gi prefetch — both issue right after the barrier,
        // hidden under the dot loop; drained for free at the next barrier.
        float gr_ = 0.f, gz_ = 0.f, gn_ = 0.f;
        if (q == 0) {
            if (s > 0) *pptr = (_Float16)pval;
            gr_ = (float)girow[j];
            gz_ = (float)girow[256 + j];
            gn_ = (float)girow[512 + j];
        }

        float ar = 0.f, az = 0.f, an = 0.f;
        const v2h* hbase = &h2s[q * 64];
        #pragma unroll
        for (int c = 0; c < 16; ++c) {
            union { float4 f; v2h h[4]; } U;
            U.f = *(const float4*)&hbase[c * 4];
            #pragma unroll
            for (int p = 0; p < 4; ++p) {
                ar = FDOT2(wr2[c * 4 + p], U.h[p], ar);
                az = FDOT2(wz2[c * 4 + p], U.h[p], az);
                an = FDOT2(wn2[c * 4 + p], U.h[p], an);
            }
        }
        if (q == 1) { parts[0][j] = ar; parts[1][j] = az; parts[2][j] = an; }
        __syncthreads();                    // partials visible; all h2s reads done

        if (q == 0) {
            const float sr = ar + parts[0][j] + br;
            const float sz = az + parts[1][j] + bzb;
            const float sn = an + parts[2][j] + bnb;
            const float r = 1.f / (1.f + __expf(-(gr_ + sr)));
            const float z = 1.f / (1.f + __expf(-(gz_ + sz)));
            const float xa = gn_ + r * sn;
            const float texp = __expf(2.f * xa);
            const float n = 1.f - 2.f / (texp + 1.f);   // tanh(xa)
            const float hnew = (1.f - z) * n + z * hprev;
            hprev = hnew;
            pptr = eptr; pval = hnew;       // store deferred to next iteration
            const float hnb = __shfl_xor(hnew, 1);   // neighbor j^1 (same wave)
            if ((j & 1) == 0) {
                v2h hv; hv[0] = (_Float16)hnew; hv[1] = (_Float16)hnb;
                h2s[j >> 1] = hv;
            }
        }
        girow += gstep;
        eptr += estep;
        __syncthreads();                    // h2s updated before next reads
    }
    if (q == 0) *pptr = (_Float16)pval;     // flush final pending store
}

// ---------------------------------------------------------------------------
// K3: sim via f16 MFMA 16x16x32.  S[b,t,j] = sum_d (ctx*w2)[t,d]*ec[j,d] + act
// Per (seq,b): M=512(t) in 4 tiles of 128, N=128(j), K=512.
// A staged with w2 pre-scale (v_pk_mul_f16); fused rowmax in C-layout epilogue.
// ---------------------------------------------------------------------------
__global__ __launch_bounds__(256) void sim_mfma(
    const _Float16* __restrict__ e_src, const _Float16* __restrict__ e_tgt,
    const _Float16* __restrict__ e_cmnt, const _Float16* __restrict__ w2h,
    const float* __restrict__ w2,
    const int* __restrict__ src_action, const int* __restrict__ tgt_action,
    float* __restrict__ S, float* __restrict__ rowmaxP)
{
    const int sb = (int)blockIdx.z;          // seq*32 + b
    const int seq = sb >> 5, b = sb & 31;
    const int t0 = blockIdx.x * 128;
    const _Float16* ctx = ((seq == 0) ? e_src : e_tgt) + (size_t)b * 512 * 512;
    const _Float16* ec = e_cmnt + (size_t)b * 128 * 512;
    const int* act = (seq == 0) ? src_action : tgt_action;

    __shared__ __align__(16) _Float16 As[128 * LP];
    __shared__ __align__(16) _Float16 Bs[128 * LP];
    const int tid = threadIdx.x;
    const int wave = tid >> 6, lane = tid & 63;
    const int quad = lane >> 4, l16 = lane & 15;
    const int wm = (wave & 1) * 64, wn = (wave >> 1) * 64;
    const int sr = tid >> 2;            // 0..63
    const int sk = (tid & 3) * 8;       // 0,8,16,24

    const _Float16* ga0 = ctx + (size_t)(t0 + sr) * 512 + sk;
    const _Float16* ga1 = ctx + (size_t)(t0 + sr + 64) * 512 + sk;
    const _Float16* gb0 = ec + (size_t)sr * 512 + sk;
    const _Float16* gb1 = ec + (size_t)(sr + 64) * 512 + sk;

    f32x4 acc[4][4];
    #pragma unroll
    for (int i = 0; i < 4; ++i)
        #pragma unroll
        for (int j = 0; j < 4; ++j) acc[i][j] = (f32x4){0.f, 0.f, 0.f, 0.f};

    for (int k0 = 0; k0 < 512; k0 += 32) {
        v8h a0 = *(const v8h*)(ga0 + k0);
        v8h a1 = *(const v8h*)(ga1 + k0);
        const v8h b0 = *(const v8h*)(gb0 + k0);
        const v8h b1 = *(const v8h*)(gb1 + k0);
        const v8h w8 = *(const v8h*)(w2h + k0 + sk);
        a0 = a0 * w8;                                   // v_pk_mul_f16 x4
        a1 = a1 * w8;
        __syncthreads();
        *(v8h*)&As[sr * LP + sk] = a0;
        *(v8h*)&As[(sr + 64) * LP + sk] = a1;
        *(v8h*)&Bs[sr * LP + sk] = b0;
        *(v8h*)&Bs[(sr + 64) * LP + sk] = b1;
        __syncthreads();
        v8h af[4], bf[4];
        #pragma unroll
        for (int i = 0; i < 4; ++i)
            af[i] = *(const v8h*)&As[(wm + i * 16 + l16) * LP + quad * 8];
        #pragma unroll
        for (int j = 0; j < 4; ++j)
            bf[j] = *(const v8h*)&Bs[(wn + j * 16 + l16) * LP + quad * 8];
        #pragma unroll
        for (int i = 0; i < 4; ++i)
            #pragma unroll
            for (int j = 0; j < 4; ++j)
                acc[i][j] = __builtin_amdgcn_mfma_f32_16x16x32_f16(af[i], bf[j], acc[i][j], 0, 0, 0);
    }

    const float w2a = w2[512];
    #pragma unroll
    for (int i = 0; i < 4; ++i) {
        #pragma unroll
        for (int reg = 0; reg < 4; ++reg) {
            const int t = t0 + wm + i * 16 + quad * 4 + reg;
            const float aterm = (float)act[b * 512 + t] * w2a;
            float m = -1e30f;
            #pragma unroll
            for (int j = 0; j < 4; ++j) {
                const float v = acc[i][j][reg] + aterm;
                S[((size_t)(sb * 512 + t)) * 128 + wn + j * 16 + l16] = v;
                m = fmaxf(m, v);
            }
            m = fmaxf(m, __shfl_xor(m, 1));
            m = fmaxf(m, __shfl_xor(m, 2));
            m = fmaxf(m, __shfl_xor(m, 4));
            m = fmaxf(m, __shfl_xor(m, 8));
            if (l16 == 0)
                rowmaxP[(size_t)(wave >> 1) * 32768 + sb * 512 + t] = m;
        }
    }
}

// K5: softmax over t (512) per (seq,b); combines the 2 j-tile max partials
__global__ __launch_bounds__(256) void softmax_kernel(const float* __restrict__ rowmaxP, float* __restrict__ bw)
{
    const int base = blockIdx.x * 512;
    const int tid = threadIdx.x;
    __shared__ float red[256];
    const float v0 = fmaxf(rowmaxP[base + tid], rowmaxP[32768 + base + tid]);
    const float v1 = fmaxf(rowmaxP[base + 256 + tid], rowmaxP[32768 + base + 256 + tid]);
    red[tid] = fmaxf(v0, v1);
    __syncthreads();
    for (int off = 128; off > 0; off >>= 1) {
        if (tid < off) red[tid] = fmaxf(red[tid], red[tid + off]);
        __syncthreads();
    }
    const float M = red[0];
    __syncthreads();
    const float e0 = __expf(v0 - M), e1 = __expf(v1 - M);
    red[tid] = e0 + e1;
    __syncthreads();
    for (int off = 128; off > 0; off >>= 1) {
        if (tid < off) red[tid] += red[tid + off];
        __syncthreads();
    }
    const float inv = 1.f / red[0];
    bw[base + tid] = e0 * inv;
    bw[base + 256 + tid] = e1 * inv;
}

// K6: outSP[c][sb*128+j] = sum_{t in chunk c} bw[sb,t] * S[sb,t,j]
__global__ __launch_bounds__(256) void weighted_kernel(
    const float* __restrict__ S, const float* __restrict__ bw, float* __restrict__ outSP)
{
    const int sb = blockIdx.x;          // seq*32 + b
    const int ch = blockIdx.y;          // t-chunk 0..7
    const int tid = threadIdx.x;
    const int j = tid & 127, half = tid >> 7;
    const float* Sb = S + (size_t)sb * 512 * 128;
    const float* w = bw + sb * 512;
    const int tb = ch * 64 + half * 32;
    float acc = 0.f;
    for (int t = tb; t < tb + 32; ++t)
        acc = fmaf(w[t], Sb[(size_t)t * 128 + j], acc);
    __shared__ float red[256];
    red[tid] = acc;
    __syncthreads();
    if (half == 0) outSP[(size_t)ch * 8192 + sb * 128 + j] = red[j] + red[128 + j];
}

// K7: sum chunk partials; write S_diff and result into d_out
__global__ __launch_bounds__(256) void final_kernel(
    const float* __restrict__ outSP, const float* __restrict__ rank_w,
    const float* __restrict__ rank_b, float* __restrict__ out)
{
    __shared__ float sArr[8192];
    const int tid = threadIdx.x;
    for (int q = tid; q < 8192; q += 256) {
        float s = 0.f;
        #pragma unroll
        for (int c = 0; c < 8; ++c) s += outSP[(size_t)c * 8192 + q];
        sArr[q] = s;
    }
    __syncthreads();
    for (int q = tid; q < 8192; q += 256) {
        const int b = q >> 8, c = q & 255;
        out[32 + q] = (c < 128) ? sArr[b * 128 + c] : sArr[4096 + b * 128 + (c - 128)];
    }
    if (tid < 32) {
        float acc = rank_b[0];
        for (int c = 0; c < 128; ++c) acc = fmaf(sArr[tid * 128 + c], rank_w[c], acc);
        for (int c = 0; c < 128; ++c) acc = fmaf(sArr[4096 + tid * 128 + c], rank_w[128 + c], acc);
        out[tid] = acc;
    }
}

// ---------------------------------------------------------------------------
extern "C" void kernel_launch(void* const* d_in, const int* in_sizes, int n_in,
                              void* d_out, int out_size, void* d_ws, size_t ws_size,
                              hipStream_t stream)
{
    const int* cmnt       = (const int*)d_in[0];
    const int* src_token  = (const int*)d_in[1];
    const int* tgt_token  = (const int*)d_in[2];
    const int* src_action = (const int*)d_in[3];
    const int* tgt_action = (const int*)d_in[4];
    const float* emb    = (const float*)d_in[5];
    const float* wih_f  = (const float*)d_in[6];
    const float* whh_f  = (const float*)d_in[7];
    const float* bih_f  = (const float*)d_in[8];
    const float* bhh_f  = (const float*)d_in[9];
    const float* wih_b  = (const float*)d_in[10];
    const float* whh_b  = (const float*)d_in[11];
    const float* bih_b  = (const float*)d_in[12];
    const float* bhh_b  = (const float*)d_in[13];
    const float* w2     = (const float*)d_in[14];
    const float* rank_w = (const float*)d_in[15];
    const float* rank_b = (const float*)d_in[16];
    float* out = (float*)d_out;

    // Workspace layout (units: fp32 slots). e_* and gi are fp16.
    float* ws = (float*)d_ws;
    size_t off = 0;
    int*   tok_all = (int*)(ws + off); off += 36864;
    short* Bt_bf16 = (short*)(ws + off); off += 196608;       // 1536x256 bf16
    float* whhT   = ws + off; off += 393216;
    float* bihc   = ws + off; off += 1536;
    float* bhhc   = ws + off; off += 1536;
    _Float16* w2h = (_Float16*)(ws + off); off += 256;        // 512 halfs
    float* rowmaxP = ws + off; off += 65536;                  // 2 x 32768
    float* bw     = ws + off; off += 32768;
    float* outSP  = ws + off; off += 65536;                   // 8 x 8192
    _Float16* e_src  = (_Float16*)(ws + off); off += 4194304; // 8.4M halfs
    _Float16* e_tgt  = (_Float16*)(ws + off); off += 4194304;
    _Float16* e_cmnt = (_Float16*)(ws + off); off += 1048576; // 2.1M halfs
    float* S      = ws + off; off += 4194304;
    _Float16* gih = (_Float16*)(ws + off);
    const size_t avail = ws_size / 4 - off;
    // Tier A: full fp16 gi (36864 x 1536 halfs = 28311552 fp32 slots)
    const bool planP = avail >= 28311552ULL;

    hipLaunchKernelGGL(prep_kernel, dim3(512), dim3(256), 0, stream,
        cmnt, src_token, tgt_token, wih_f, wih_b, whh_f, whh_b,
        bih_f, bih_b, bhh_f, bhh_b, w2, tok_all, whhT, bihc, bhhc, Bt_bf16, w2h);

    if (planP) {
        // A_bf16 (36864x256 shorts) aliases e_src+e_tgt, consumed before gru writes e.
        short* A = (short*)e_src;
        hipLaunchKernelGGL(gatherA_kernel, dim3(4096), dim3(256), 0, stream,
            tok_all, 0, 36864, emb, A);
        hipLaunchKernelGGL(gi_mfma, dim3(288, 12), dim3(256), 0, stream,
            A, Bt_bf16, bihc, gih);
        hipLaunchKernelGGL(gru_kernel, dim3(192), dim3(512), 0, stream,
            gih, gih + (size_t)16384 * NC, gih + (size_t)32768 * NC,
            whhT, bhhc, e_src, e_tgt, e_cmnt, 0);
    } else {
        // Serial fallback: per-seq fp16 gi chunk; A aliases S
        short* A = (short*)S;
        const int starts[3] = {0, 16384, 32768};
        const int nrows[3]  = {16384, 16384, 4096};
        for (int sq = 0; sq < 3; ++sq) {
            hipLaunchKernelGGL(gatherA_kernel, dim3(4096), dim3(256), 0, stream,
                tok_all, starts[sq], nrows[sq], emb, A);
            hipLaunchKernelGGL(gi_mfma, dim3(nrows[sq] / 128, 12), dim3(256), 0, stream,
                A, Bt_bf16, bihc, gih);
            hipLaunchKernelGGL(gru_kernel, dim3(64), dim3(512), 0, stream,
                gih, gih, gih, whhT, bhhc, e_src, e_tgt, e_cmnt, 2 * sq);
        }
    }

    hipLaunchKernelGGL(sim_mfma, dim3(4, 1, 64), dim3(256), 0, stream,
        e_src, e_tgt, e_cmnt, w2h, w2, src_action, tgt_action, S, rowmaxP);
    hipLaunchKernelGGL(softmax_kernel, dim3(64), dim3(256), 0, stream, rowmaxP, bw);
    hipLaunchKernelGGL(weighted_kernel, dim3(64, 8), dim3(256), 0, stream, S, bw, outSP);
    hipLaunchKernelGGL(final_kernel, dim3(1), dim3(256), 0, stream, outSP, rank_w, rank_b, out);
}